// Round 4
// baseline (1358.943 us; speedup 1.0000x reference)
//
#include <hip/hip_runtime.h>

// VQ nearest-neighbor: argmin_k ||c_k||^2 - 2 x_n . c_k
// N=32768 rows, K=8192 codes, D=512, fp32 in, int32 indices out.
//
// Round 4: 2-phase double-buffered pipeline with counted vmcnt (T3/T4):
// issue next K-step's global_load_lds before consuming current buffer,
// s_waitcnt vmcnt(8) (never 0 mid-loop), raw s_barrier pair, setprio(1)
// around the MFMA cluster (T5). Keeps round-3's verified LDS XOR-swizzle
// (0 bank conflicts) and fused 3-term bf16-split MFMA. cbsqr fused into
// the codebook split kernel.

#define D_DIM 512
#define EPS_GAP 1.5e-6f
#define KSPLIT 8
#define RPB 4

typedef __attribute__((ext_vector_type(8))) short short8;
typedef __attribute__((ext_vector_type(4))) float f32x4;
typedef __attribute__((ext_vector_type(4))) unsigned short us4;

#define VM8 asm volatile("s_waitcnt vmcnt(8)" ::: "memory")
#define VM0 asm volatile("s_waitcnt vmcnt(0)" ::: "memory")
#define LG0 asm volatile("s_waitcnt lgkmcnt(0)" ::: "memory")

__device__ __forceinline__ unsigned short f2bf(float x) {
    unsigned u = __float_as_uint(x);
    u += 0x7fffu + ((u >> 16) & 1u);          // RNE
    return (unsigned short)(u >> 16);
}
__device__ __forceinline__ float bf2f(unsigned short h) {
    return __uint_as_float(((unsigned)h) << 16);
}

__device__ __forceinline__ void gload_lds16(const void* g, void* l) {
    __builtin_amdgcn_global_load_lds(
        (const __attribute__((address_space(1))) unsigned int*)g,
        (__attribute__((address_space(3))) unsigned int*)l, 16, 0, 0);
}

// ---- pass 0a: split X fp32 -> (hi, lo) bf16, elementwise ----
__global__ __launch_bounds__(256) void split_kernel(const float* __restrict__ src,
                                                    unsigned short* __restrict__ hi,
                                                    unsigned short* __restrict__ lo,
                                                    int n4) {
    int i = blockIdx.x * blockDim.x + threadIdx.x;
    int stride = gridDim.x * blockDim.x;
    for (; i < n4; i += stride) {
        float4 v = ((const float4*)src)[i];
        us4 h, l;
        h.x = f2bf(v.x); l.x = f2bf(v.x - bf2f(h.x));
        h.y = f2bf(v.y); l.y = f2bf(v.y - bf2f(h.y));
        h.z = f2bf(v.z); l.z = f2bf(v.z - bf2f(h.z));
        h.w = f2bf(v.w); l.w = f2bf(v.w - bf2f(h.w));
        ((us4*)hi)[i] = h;
        ((us4*)lo)[i] = l;
    }
}

// ---- pass 0b: split CB + ||c||^2 in one read (wave per code row) ----
__global__ __launch_bounds__(256) void splitcb_kernel(const float* __restrict__ cb,
                                                      unsigned short* __restrict__ hi,
                                                      unsigned short* __restrict__ lo,
                                                      float* __restrict__ sq,
                                                      int* __restrict__ cnt, int K) {
    if (blockIdx.x == 0 && threadIdx.x == 0 && cnt) *cnt = 0;
    int gtid = blockIdx.x * blockDim.x + threadIdx.x;
    int w = gtid >> 6;
    int lane = gtid & 63;
    if (w >= K) return;
    size_t base = (size_t)w * D_DIM + lane * 8;
    const float4* r4 = (const float4*)(cb + base);
    float4 u = r4[0], v = r4[1];
    float s = u.x*u.x + u.y*u.y + u.z*u.z + u.w*u.w
            + v.x*v.x + v.y*v.y + v.z*v.z + v.w*v.w;
    us4 h0, l0, h1, l1;
    h0.x = f2bf(u.x); l0.x = f2bf(u.x - bf2f(h0.x));
    h0.y = f2bf(u.y); l0.y = f2bf(u.y - bf2f(h0.y));
    h0.z = f2bf(u.z); l0.z = f2bf(u.z - bf2f(h0.z));
    h0.w = f2bf(u.w); l0.w = f2bf(u.w - bf2f(h0.w));
    h1.x = f2bf(v.x); l1.x = f2bf(v.x - bf2f(h1.x));
    h1.y = f2bf(v.y); l1.y = f2bf(v.y - bf2f(h1.y));
    h1.z = f2bf(v.z); l1.z = f2bf(v.z - bf2f(h1.z));
    h1.w = f2bf(v.w); l1.w = f2bf(v.w - bf2f(h1.w));
    ((us4*)(hi + base))[0] = h0; ((us4*)(hi + base))[1] = h1;
    ((us4*)(lo + base))[0] = l0; ((us4*)(lo + base))[1] = l1;
#pragma unroll
    for (int off = 32; off; off >>= 1) s += __shfl_xor(s, off);
    if (lane == 0) sq[w] = s;
}

// ---- pass 1: fused MFMA dists + register top-2, 2-phase pipeline ----
// grid = (N/128)*KSPLIT blocks, 256 threads (4 waves 2x2).
__global__ __launch_bounds__(256, 2) void vq_mfma_kernel(
        const unsigned short* __restrict__ Xh, const unsigned short* __restrict__ Xl,
        const unsigned short* __restrict__ Ch, const unsigned short* __restrict__ Cl,
        const float* __restrict__ cbs,
        float* __restrict__ pd1, int* __restrict__ pi1, float* __restrict__ pd2,
        int N, int K) {

    __shared__ unsigned short Ah[2][128 * 32], Al[2][128 * 32];
    __shared__ unsigned short Bh[2][128 * 32], Bl[2][128 * 32];
    __shared__ float redD1[2][128];
    __shared__ int   redI1[2][128];
    __shared__ float redD2[2][128];

    const int tid  = threadIdx.x;
    const int lane = tid & 63;
    const int wid  = tid >> 6;
    const int wr   = wid >> 1;       // row half
    const int wc   = wid & 1;        // col half
    const int bid  = blockIdx.x;
    const int split    = bid & (KSPLIT - 1);
    const int rowBase  = (bid >> 3) * 128;
    const int kPerSplit = K / KSPLIT;
    const int splitBase = split * kPerSplit;
    const int NTCOL = kPerSplit / 128;

    // staging: lane l covers LDS row wid*32+(l>>2), 16B chunk p=l&3.
    // swizzle s(r)=(r>>1)&3 -> source chunk = p ^ s = (l&3)^((l>>3)&3).
    const int l4  = lane >> 2;
    const int swz = ((lane & 3) ^ ((lane >> 3) & 3)) * 8;
    const size_t gA0 = (size_t)(rowBase + wid * 32 + l4) * D_DIM + swz;
    const size_t gB0 = (size_t)(wid * 32 + l4) * D_DIM + swz;
    const int l0 = wid * 1024 + lane * 8;      // linear LDS dest (shorts)

    // read side: row rA+16m, chunk c=lane>>4 -> pos c^s(row), s = (lane>>1)&3.
    const int rA = wr * 64 + (lane & 15);
    const int rB = wc * 64 + (lane & 15);
    const int kSwz = (((lane >> 4) ^ ((lane >> 1) & 3))) * 8;

    float bd1[4][4], bd2[4][4];
    int   bi1[4][4];
#pragma unroll
    for (int m = 0; m < 4; ++m)
#pragma unroll
        for (int r = 0; r < 4; ++r) {
            bd1[m][r] = 3.4e38f; bd2[m][r] = 3.4e38f; bi1[m][r] = 0x7fffffff;
        }

#define STAGE(buf, ko)                                                       \
    do {                                                                     \
        gload_lds16(Xh  + gA0 + (ko),              &Ah[buf][l0]);            \
        gload_lds16(Xh  + gA0 + (ko) + 16 * D_DIM, &Ah[buf][l0 + 512]);      \
        gload_lds16(Xl  + gA0 + (ko),              &Al[buf][l0]);            \
        gload_lds16(Xl  + gA0 + (ko) + 16 * D_DIM, &Al[buf][l0 + 512]);      \
        gload_lds16(ChB + gB0 + (ko),              &Bh[buf][l0]);            \
        gload_lds16(ChB + gB0 + (ko) + 16 * D_DIM, &Bh[buf][l0 + 512]);      \
        gload_lds16(ClB + gB0 + (ko),              &Bl[buf][l0]);            \
        gload_lds16(ClB + gB0 + (ko) + 16 * D_DIM, &Bl[buf][l0 + 512]);      \
    } while (0)

    for (int ct = 0; ct < NTCOL; ++ct) {
        const int codeBase = splitBase + ct * 128;
        const unsigned short* ChB = Ch + (size_t)codeBase * D_DIM;
        const unsigned short* ClB = Cl + (size_t)codeBase * D_DIM;

        f32x4 acc[4][4];
#pragma unroll
        for (int m = 0; m < 4; ++m)
#pragma unroll
            for (int n = 0; n < 4; ++n) acc[m][n] = (f32x4){0.f, 0.f, 0.f, 0.f};

        STAGE(0, 0);   // prologue: kt=0 into buf0

        for (int kt = 0; kt < 16; ++kt) {
            const int cur = kt & 1;
            if (kt < 15) {
                STAGE(cur ^ 1, (kt + 1) * 32);   // prefetch next step
                VM8;                              // counted: wait cur buf only
            } else {
                VM0;                              // last step: drain
            }
            __builtin_amdgcn_s_barrier();         // cur buf fully staged
            __builtin_amdgcn_sched_barrier(0);

            const unsigned short* AhC = &Ah[cur][0];
            const unsigned short* AlC = &Al[cur][0];
            const unsigned short* BhC = &Bh[cur][0];
            const unsigned short* BlC = &Bl[cur][0];
            short8 bvh[4], bvl[4], avh[4], avl[4];
#pragma unroll
            for (int n = 0; n < 4; ++n) {
                bvh[n] = *(const short8*)&BhC[(rB + n * 16) * 32 + kSwz];
                bvl[n] = *(const short8*)&BlC[(rB + n * 16) * 32 + kSwz];
            }
#pragma unroll
            for (int m = 0; m < 4; ++m) {
                avh[m] = *(const short8*)&AhC[(rA + m * 16) * 32 + kSwz];
                avl[m] = *(const short8*)&AlC[(rA + m * 16) * 32 + kSwz];
            }
            LG0;                                  // reads landed in regs
            __builtin_amdgcn_sched_barrier(0);    // rule 18: pin MFMA below
            __builtin_amdgcn_s_barrier();         // all waves done reading cur

            __builtin_amdgcn_s_setprio(1);
#pragma unroll
            for (int m = 0; m < 4; ++m)
#pragma unroll
                for (int n = 0; n < 4; ++n) {
                    acc[m][n] = __builtin_amdgcn_mfma_f32_16x16x32_bf16(
                        avh[m], bvh[n], acc[m][n], 0, 0, 0);
                    acc[m][n] = __builtin_amdgcn_mfma_f32_16x16x32_bf16(
                        avl[m], bvh[n], acc[m][n], 0, 0, 0);
                    acc[m][n] = __builtin_amdgcn_mfma_f32_16x16x32_bf16(
                        avh[m], bvl[n], acc[m][n], 0, 0, 0);
                }
            __builtin_amdgcn_s_setprio(0);
        }

        // per-tile top-2 update (registers only; codes ascend)
        float c2[4]; int cc[4];
#pragma unroll
        for (int n = 0; n < 4; ++n) {
            cc[n] = codeBase + wc * 64 + n * 16 + (lane & 15);
            c2[n] = cbs[cc[n]];
        }
#pragma unroll
        for (int m = 0; m < 4; ++m)
#pragma unroll
            for (int r = 0; r < 4; ++r)
#pragma unroll
                for (int n = 0; n < 4; ++n) {
                    float dist = fmaf(-2.f, acc[m][n][r], c2[n]);
                    bool lt = dist < bd1[m][r];
                    bd2[m][r] = lt ? bd1[m][r] : fminf(bd2[m][r], dist);
                    bi1[m][r] = lt ? cc[n] : bi1[m][r];
                    bd1[m][r] = lt ? dist : bd1[m][r];
                }
    }
#undef STAGE

    // final cross-lane reduce (once per block)
#pragma unroll
    for (int m = 0; m < 4; ++m)
#pragma unroll
        for (int r = 0; r < 4; ++r) {
            float d1 = bd1[m][r]; int i1 = bi1[m][r]; float d2 = bd2[m][r];
#pragma unroll
            for (int off = 1; off < 16; off <<= 1) {
                float od1 = __shfl_xor(d1, off);
                int   oi1 = __shfl_xor(i1, off);
                float od2 = __shfl_xor(d2, off);
                bool bwin = (od1 < d1) || (od1 == d1 && oi1 < i1);
                if (bwin) { d2 = fminf(od2, d1); d1 = od1; i1 = oi1; }
                else      { d2 = fminf(d2, od1); }
            }
            if ((lane & 15) == 0) {
                int rowInBlk = wr * 64 + m * 16 + (lane >> 4) * 4 + r;
                redD1[wc][rowInBlk] = d1;
                redI1[wc][rowInBlk] = i1;
                redD2[wc][rowInBlk] = d2;
            }
        }
    __syncthreads();
    if (tid < 128) {
        float d1 = redD1[0][tid]; int i1 = redI1[0][tid]; float d2 = redD2[0][tid];
        float od1 = redD1[1][tid]; int oi1 = redI1[1][tid]; float od2 = redD2[1][tid];
        bool bwin = (od1 < d1) || (od1 == d1 && oi1 < i1);
        if (bwin) { d2 = fminf(od2, d1); d1 = od1; i1 = oi1; }
        else      { d2 = fminf(d2, od1); }
        size_t p = (size_t)split * N + (rowBase + tid);
        pd1[p] = d1; pi1[p] = i1; pd2[p] = d2;
    }
}

// ---- pass 2: merge split partials, emit index + near-tie flags ----
__global__ __launch_bounds__(256) void combine2_kernel(
        const float* __restrict__ pd1, const int* __restrict__ pi1,
        const float* __restrict__ pd2,
        int* __restrict__ out, int* __restrict__ flags, int* __restrict__ cnt,
        int N, int S) {
    int row = blockIdx.x * blockDim.x + threadIdx.x;
    if (row >= N) return;
    float d1 = pd1[row]; int i1 = pi1[row]; float d2 = pd2[row];
    for (int s = 1; s < S; ++s) {
        size_t p = (size_t)s * N + row;
        float od1 = pd1[p]; int oi1 = pi1[p]; float od2 = pd2[p];
        bool bwin = (od1 < d1) || (od1 == d1 && oi1 < i1);
        if (bwin) { d2 = fminf(od2, d1); d1 = od1; i1 = oi1; }
        else      { d2 = fminf(d2, od1); }
    }
    out[row] = i1;
    if (d2 - d1 < EPS_GAP) {
        int f = atomicAdd(cnt, 1);
        flags[f] = row;
    }
}

// ---- pass 3: exact fp32 re-solve of flagged rows (RPB rows/block) ----
__global__ __launch_bounds__(256) void refine_kernel(
        const float* __restrict__ X, const float* __restrict__ CB,
        const float* __restrict__ cbs,
        const int* __restrict__ flags, const int* __restrict__ cnt,
        int* __restrict__ out, int K) {
    __shared__ float xs[RPB][D_DIM];
    __shared__ float rD[RPB][4];
    __shared__ int   rI[RPB][4];
    const int nf = *cnt;
    for (int f0 = blockIdx.x * RPB; f0 < nf; f0 += gridDim.x * RPB) {
        const int nr = min(RPB, nf - f0);
        __syncthreads();
        for (int i = threadIdx.x; i < nr * D_DIM; i += 256)
            xs[i >> 9][i & 511] = X[(size_t)flags[f0 + (i >> 9)] * D_DIM + (i & 511)];
        __syncthreads();
        float bd[RPB]; int bi[RPB];
#pragma unroll
        for (int rr = 0; rr < RPB; ++rr) { bd[rr] = 3.4e38f; bi[rr] = 0x7fffffff; }
        for (int c = threadIdx.x; c < K; c += 256) {
            const float4* cp = (const float4*)(CB + (size_t)c * D_DIM);
            float dot[RPB] = {0.f, 0.f, 0.f, 0.f};
#pragma unroll 4
            for (int d = 0; d < D_DIM / 4; ++d) {
                float4 cv = cp[d];
#pragma unroll
                for (int rr = 0; rr < RPB; ++rr) {
                    float4 xv = *(const float4*)&xs[rr][d * 4];
                    dot[rr] = fmaf(xv.x, cv.x, dot[rr]);
                    dot[rr] = fmaf(xv.y, cv.y, dot[rr]);
                    dot[rr] = fmaf(xv.z, cv.z, dot[rr]);
                    dot[rr] = fmaf(xv.w, cv.w, dot[rr]);
                }
            }
            float c2v = cbs[c];
#pragma unroll
            for (int rr = 0; rr < RPB; ++rr) {
                float dist = fmaf(-2.f, dot[rr], c2v);
                if (dist < bd[rr]) { bd[rr] = dist; bi[rr] = c; }
            }
        }
#pragma unroll
        for (int rr = 0; rr < RPB; ++rr) {
            float d = bd[rr]; int i = bi[rr];
#pragma unroll
            for (int off = 1; off < 64; off <<= 1) {
                float od = __shfl_xor(d, off);
                int   oi = __shfl_xor(i, off);
                if (od < d || (od == d && oi < i)) { d = od; i = oi; }
            }
            if ((threadIdx.x & 63) == 0) {
                rD[rr][threadIdx.x >> 6] = d;
                rI[rr][threadIdx.x >> 6] = i;
            }
        }
        __syncthreads();
        if (threadIdx.x < RPB && (int)threadIdx.x < nr) {
            int rr = threadIdx.x;
            float d = rD[rr][0]; int i = rI[rr][0];
            for (int w = 1; w < 4; ++w)
                if (rD[rr][w] < d || (rD[rr][w] == d && rI[rr][w] < i)) {
                    d = rD[rr][w]; i = rI[rr][w];
                }
            out[flags[f0 + rr]] = i;
        }
    }
}

// ================= fp32 fallback (generic shapes) =================
#define BM 128
#define BN 128
#define BD 16

__global__ __launch_bounds__(256) void cbsqr_kernel(const float* __restrict__ cb,
                                                    float* __restrict__ out, int K) {
    int gtid = blockIdx.x * blockDim.x + threadIdx.x;
    int w = gtid >> 6;
    int lane = gtid & 63;
    if (w >= K) return;
    const float4* r4 = (const float4*)(cb + (size_t)w * D_DIM) + lane * 2;
    float4 u = r4[0], v = r4[1];
    float s = u.x*u.x + u.y*u.y + u.z*u.z + u.w*u.w
            + v.x*v.x + v.y*v.y + v.z*v.z + v.w*v.w;
#pragma unroll
    for (int off = 32; off; off >>= 1) s += __shfl_xor(s, off);
    if (lane == 0) out[w] = s;
}

__global__ __launch_bounds__(128) void vq_fp32_kernel(
        const float* __restrict__ X, const float* __restrict__ CB,
        const float* __restrict__ cbs,
        float* __restrict__ pd, int* __restrict__ pi,
        int* __restrict__ out, int N, int K, int nsplit) {

    __shared__ float As[BD][BM + 4];
    __shared__ float Bs[BD][BN + 4];

    const int tid = threadIdx.x;
    const int tx = tid & 7;
    const int ty = tid >> 3;
    const int rowBase = blockIdx.x * BM;
    const int split = blockIdx.y;
    const int kPer = K / nsplit;
    const int c0 = split * kPer, c1 = c0 + kPer;
    const int ldRow = tid >> 2;
    const int ldCol = (tid & 3) * 4;

    float bestD[8]; int bestI[8];
#pragma unroll
    for (int i = 0; i < 8; ++i) { bestD[i] = 3.4e38f; bestI[i] = 0; }

    for (int ct = c0; ct < c1; ct += BN) {
        float acc[8][16];
#pragma unroll
        for (int i = 0; i < 8; ++i)
#pragma unroll
            for (int j = 0; j < 16; ++j) acc[i][j] = 0.f;

        for (int dt = 0; dt < D_DIM; dt += BD) {
#pragma unroll
            for (int p = 0; p < 4; ++p) {
                int r = ldRow + p * 32;
                float4 av = *(const float4*)&X[(size_t)(rowBase + r) * D_DIM + dt + ldCol];
                float4 bv = *(const float4*)&CB[(size_t)(ct + r) * D_DIM + dt + ldCol];
                As[ldCol + 0][r] = av.x; As[ldCol + 1][r] = av.y;
                As[ldCol + 2][r] = av.z; As[ldCol + 3][r] = av.w;
                Bs[ldCol + 0][r] = bv.x; Bs[ldCol + 1][r] = bv.y;
                Bs[ldCol + 2][r] = bv.z; Bs[ldCol + 3][r] = bv.w;
            }
            __syncthreads();
#pragma unroll
            for (int d = 0; d < BD; ++d) {
                float4 a0 = *(const float4*)&As[d][ty * 4];
                float4 a1 = *(const float4*)&As[d][64 + ty * 4];
                float4 b0 = *(const float4*)&Bs[d][ 0 + tx * 4];
                float4 b1 = *(const float4*)&Bs[d][32 + tx * 4];
                float4 b2 = *(const float4*)&Bs[d][64 + tx * 4];
                float4 b3 = *(const float4*)&Bs[d][96 + tx * 4];
                float a[8] = {a0.x,a0.y,a0.z,a0.w,a1.x,a1.y,a1.z,a1.w};
                float b[16] = {b0.x,b0.y,b0.z,b0.w, b1.x,b1.y,b1.z,b1.w,
                               b2.x,b2.y,b2.z,b2.w, b3.x,b3.y,b3.z,b3.w};
#pragma unroll
                for (int i = 0; i < 8; ++i)
#pragma unroll
                    for (int j = 0; j < 16; ++j)
                        acc[i][j] = fmaf(a[i], b[j], acc[i][j]);
            }
            __syncthreads();
        }
#pragma unroll
        for (int j = 0; j < 16; ++j) {
            int code = ct + (j >> 2) * 32 + tx * 4 + (j & 3);
            float c2v = cbs[code];
#pragma unroll
            for (int i = 0; i < 8; ++i) {
                float dist = fmaf(-2.f, acc[i][j], c2v);
                if (dist < bestD[i]) { bestD[i] = dist; bestI[i] = code; }
            }
        }
    }
#pragma unroll
    for (int i = 0; i < 8; ++i) {
        float bd = bestD[i]; int bi = bestI[i];
#pragma unroll
        for (int off = 1; off < 8; off <<= 1) {
            float od = __shfl_xor(bd, off);
            int   oi = __shfl_xor(bi, off);
            if (od < bd || (od == bd && oi < bi)) { bd = od; bi = oi; }
        }
        if (tx == 0) {
            int row = rowBase + ((i < 4) ? ty * 4 + i : 64 + ty * 4 + (i - 4));
            if (nsplit == 1) out[row] = bi;
            else {
                pd[(size_t)row * nsplit + split] = bd;
                pi[(size_t)row * nsplit + split] = bi;
            }
        }
    }
}

__global__ __launch_bounds__(256) void combine_fp32_kernel(
        const float* __restrict__ pd, const int* __restrict__ pi,
        int* __restrict__ out, int N, int S) {
    int r = blockIdx.x * blockDim.x + threadIdx.x;
    if (r >= N) return;
    float bd = pd[(size_t)r * S];
    int bi = pi[(size_t)r * S];
    for (int s = 1; s < S; ++s) {
        float d = pd[(size_t)r * S + s];
        int i = pi[(size_t)r * S + s];
        if (d < bd || (d == bd && i < bi)) { bd = d; bi = i; }
    }
    out[r] = bi;
}

// =========================== launcher ===========================
extern "C" void kernel_launch(void* const* d_in, const int* in_sizes, int n_in,
                              void* d_out, int out_size, void* d_ws, size_t ws_size,
                              hipStream_t stream) {
    const float* X  = (const float*)d_in[0];
    const float* CB = (const float*)d_in[1];
    const int N = in_sizes[0] / D_DIM;
    const int K = in_sizes[1] / D_DIM;
    int* out = (int*)d_out;

    size_t o = 0;
    auto take = [&](size_t bytes) { size_t r = o; o += (bytes + 255) & ~(size_t)255; return r; };
    size_t oCbs = take((size_t)K * 4);
    size_t oXh  = take((size_t)N * D_DIM * 2);
    size_t oXl  = take((size_t)N * D_DIM * 2);
    size_t oCh  = take((size_t)K * D_DIM * 2);
    size_t oCl  = take((size_t)K * D_DIM * 2);
    size_t oPd1 = take((size_t)N * KSPLIT * 4);
    size_t oPi1 = take((size_t)N * KSPLIT * 4);
    size_t oPd2 = take((size_t)N * KSPLIT * 4);
    size_t oFlg = take((size_t)N * 4);
    size_t oCnt = take(256);
    const size_t need = o;

    char* ws = (char*)d_ws;
    float* cbs = (float*)(ws + oCbs);

    if (ws_size >= need && (N % 128) == 0 && (K % (128 * KSPLIT)) == 0) {
        unsigned short* Xh = (unsigned short*)(ws + oXh);
        unsigned short* Xl = (unsigned short*)(ws + oXl);
        unsigned short* Ch = (unsigned short*)(ws + oCh);
        unsigned short* Cl = (unsigned short*)(ws + oCl);
        float* pd1 = (float*)(ws + oPd1);
        int*   pi1 = (int*)(ws + oPi1);
        float* pd2 = (float*)(ws + oPd2);
        int* flags = (int*)(ws + oFlg);
        int* cnt   = (int*)(ws + oCnt);

        split_kernel<<<4096, 256, 0, stream>>>(X, Xh, Xl, N * D_DIM / 4);
        splitcb_kernel<<<(K + 3) / 4, 256, 0, stream>>>(CB, Ch, Cl, cbs, cnt, K);

        vq_mfma_kernel<<<(N / 128) * KSPLIT, 256, 0, stream>>>(
            Xh, Xl, Ch, Cl, cbs, pd1, pi1, pd2, N, K);
        combine2_kernel<<<(N + 255) / 256, 256, 0, stream>>>(pd1, pi1, pd2,
                                                             out, flags, cnt, N, KSPLIT);
        refine_kernel<<<256, 256, 0, stream>>>(X, CB, cbs, flags, cnt, out, K);
    } else {
        size_t base = ((size_t)K * 4 + 255) & ~(size_t)255;
        int nsplit = 4;
        while (nsplit > 1 &&
               (ws_size < base + (size_t)N * nsplit * 8 || (K % (nsplit * BN)) != 0))
            nsplit >>= 1;
        float* pd = (float*)(ws + base);
        int*   pi = (int*)(ws + base + (size_t)N * nsplit * 4);
        cbsqr_kernel<<<(K + 3) / 4, 256, 0, stream>>>(CB, cbs, K);
        dim3 grid(N / BM, nsplit);
        vq_fp32_kernel<<<grid, 128, 0, stream>>>(X, CB, cbs, pd, pi, out, N, K, nsplit);
        if (nsplit > 1)
            combine_fp32_kernel<<<(N + 255) / 256, 256, 0, stream>>>(pd, pi, out, N, nsplit);
    }
}